// Round 7
// baseline (353.100 us; speedup 1.0000x reference)
//
#include <hip/hip_runtime.h>
#include <hip/hip_bf16.h>

// Diagonal-MVN negative mean log-prob:
//   loss = (0.5/B) * [ sum_all((t-mu)^2/sigma) + sum_all(log sigma) ] + 0.5*D*log(2*pi)
// B=16384, D=2048, all f32. Streaming reduction, ~402 MB touched (~200 MB from HBM
// after L3). Round-3 lesson: VGPR=16 serialized the loads -> latency-bound at 128 us.
// Fix: x4 manual unroll, all 12 float4 loads issued before compute, 4 accumulators.

#define LOG_2PI 1.8378770664093453f

__global__ __launch_bounds__(256) void mvn_nll_kernel(
    const float* __restrict__ mu,
    const float* __restrict__ sigma,
    const float* __restrict__ target,
    float* __restrict__ out,
    long long n4,           // total elements / 4
    float scale,            // 0.5 / B
    float const_term)       // 0.5 * D * LOG_2PI (added by block 0 only)
{
    const float4* __restrict__ mu4 = reinterpret_cast<const float4*>(mu);
    const float4* __restrict__ sg4 = reinterpret_cast<const float4*>(sigma);
    const float4* __restrict__ tg4 = reinterpret_cast<const float4*>(target);

    long long idx    = (long long)blockIdx.x * blockDim.x + threadIdx.x;
    long long stride = (long long)gridDim.x * blockDim.x;

    float acc0 = 0.0f, acc1 = 0.0f, acc2 = 0.0f, acc3 = 0.0f;

    // Main x4-unrolled loop: 12 independent float4 loads in flight per iteration.
    long long i = idx;
    for (; i + 3 * stride < n4; i += 4 * stride) {
        // ---- issue ALL loads first (MLP: 12 x 16B outstanding) ----
        float4 m0 = mu4[i];
        float4 m1 = mu4[i +     stride];
        float4 m2 = mu4[i + 2 * stride];
        float4 m3 = mu4[i + 3 * stride];
        float4 s0 = sg4[i];
        float4 s1 = sg4[i +     stride];
        float4 s2 = sg4[i + 2 * stride];
        float4 s3 = sg4[i + 3 * stride];
        float4 t0 = tg4[i];
        float4 t1 = tg4[i +     stride];
        float4 t2 = tg4[i + 2 * stride];
        float4 t3 = tg4[i + 3 * stride];

        // ---- compute (independent chains per unroll slot) ----
        {
            float d0 = t0.x - m0.x, d1 = t0.y - m0.y, d2 = t0.z - m0.z, d3 = t0.w - m0.w;
            float q = d0 * d0 * __builtin_amdgcn_rcpf(s0.x)
                    + d1 * d1 * __builtin_amdgcn_rcpf(s0.y)
                    + d2 * d2 * __builtin_amdgcn_rcpf(s0.z)
                    + d3 * d3 * __builtin_amdgcn_rcpf(s0.w);
            acc0 += q + __logf((s0.x * s0.y) * (s0.z * s0.w));
        }
        {
            float d0 = t1.x - m1.x, d1 = t1.y - m1.y, d2 = t1.z - m1.z, d3 = t1.w - m1.w;
            float q = d0 * d0 * __builtin_amdgcn_rcpf(s1.x)
                    + d1 * d1 * __builtin_amdgcn_rcpf(s1.y)
                    + d2 * d2 * __builtin_amdgcn_rcpf(s1.z)
                    + d3 * d3 * __builtin_amdgcn_rcpf(s1.w);
            acc1 += q + __logf((s1.x * s1.y) * (s1.z * s1.w));
        }
        {
            float d0 = t2.x - m2.x, d1 = t2.y - m2.y, d2 = t2.z - m2.z, d3 = t2.w - m2.w;
            float q = d0 * d0 * __builtin_amdgcn_rcpf(s2.x)
                    + d1 * d1 * __builtin_amdgcn_rcpf(s2.y)
                    + d2 * d2 * __builtin_amdgcn_rcpf(s2.z)
                    + d3 * d3 * __builtin_amdgcn_rcpf(s2.w);
            acc2 += q + __logf((s2.x * s2.y) * (s2.z * s2.w));
        }
        {
            float d0 = t3.x - m3.x, d1 = t3.y - m3.y, d2 = t3.z - m3.z, d3 = t3.w - m3.w;
            float q = d0 * d0 * __builtin_amdgcn_rcpf(s3.x)
                    + d1 * d1 * __builtin_amdgcn_rcpf(s3.y)
                    + d2 * d2 * __builtin_amdgcn_rcpf(s3.z)
                    + d3 * d3 * __builtin_amdgcn_rcpf(s3.w);
            acc3 += q + __logf((s3.x * s3.y) * (s3.z * s3.w));
        }
    }
    // Tail (not taken for 16384x2048 with 2048x256 grid, but keep it general).
    for (; i < n4; i += stride) {
        float4 m = mu4[i];
        float4 s = sg4[i];
        float4 t = tg4[i];
        float d0 = t.x - m.x, d1 = t.y - m.y, d2 = t.z - m.z, d3 = t.w - m.w;
        float q = d0 * d0 * __builtin_amdgcn_rcpf(s.x)
                + d1 * d1 * __builtin_amdgcn_rcpf(s.y)
                + d2 * d2 * __builtin_amdgcn_rcpf(s.z)
                + d3 * d3 * __builtin_amdgcn_rcpf(s.w);
        acc0 += q + __logf((s.x * s.y) * (s.z * s.w));
    }

    float acc = (acc0 + acc1) + (acc2 + acc3);

    // wave (64-lane) butterfly reduce
    #pragma unroll
    for (int off = 32; off > 0; off >>= 1)
        acc += __shfl_down(acc, off, 64);

    __shared__ float smem[4];  // 256 threads / 64 = 4 waves
    int wave = threadIdx.x >> 6;
    if ((threadIdx.x & 63) == 0) smem[wave] = acc;
    __syncthreads();

    if (threadIdx.x == 0) {
        float bsum = smem[0] + smem[1] + smem[2] + smem[3];
        float contrib = bsum * scale;           // pre-scale: atomic sum ~O(4000), no cancellation
        if (blockIdx.x == 0) contrib += const_term;
        atomicAdd(out, contrib);
    }
}

extern "C" void kernel_launch(void* const* d_in, const int* in_sizes, int n_in,
                              void* d_out, int out_size, void* d_ws, size_t ws_size,
                              hipStream_t stream) {
    const float* mu     = (const float*)d_in[0];
    const float* sigma  = (const float*)d_in[1];
    const float* target = (const float*)d_in[2];
    float* out = (float*)d_out;

    const long long D = 2048;
    const long long n = (long long)in_sizes[0];   // B * D (16384 * 2048)
    const long long B = n / D;
    const long long n4 = n / 4;

    // d_out is re-poisoned to 0xAA before every timed replay -> zero it on-stream.
    hipMemsetAsync(d_out, 0, (size_t)out_size * sizeof(float), stream);

    const int block = 256;
    const int grid  = 2048;  // 8 blocks/CU, 32 waves/CU; grid-stride the rest

    float scale      = 0.5f / (float)B;
    float const_term = 0.5f * (float)D * LOG_2PI;

    mvn_nll_kernel<<<grid, block, 0, stream>>>(mu, sigma, target, out, n4, scale, const_term);
}